// Round 2
// baseline (393.832 us; speedup 1.0000x reference)
//
#include <hip/hip_runtime.h>
#include <stdint.h>

#define NN 50000
#define NEG_SLOPE 0.2f

// output layout (element offsets)
#define IXZ_OFF    (NN * 64)
#define SKL_OFF    (NN * 64 + NN)
#define MEAN_OFF   (NN * 64 + NN + 1)
#define STD_OFF    (MEAN_OFF + NN * 64)

typedef unsigned int u32;
typedef unsigned short u16;

__device__ __forceinline__ float bf2f(u16 s) { return __uint_as_float(((u32)s) << 16); }
__device__ __forceinline__ u16 f2bf(float f) {
    u32 u = __float_as_uint(f);
    u += 0x7FFFu + ((u >> 16) & 1u);   // RNE
    return (u16)(u >> 16);
}
__device__ __forceinline__ float lo16(u32 u) { return __uint_as_float(u << 16); }
__device__ __forceinline__ float hi16(u32 u) { return __uint_as_float(u & 0xFFFF0000u); }
__device__ __forceinline__ float red32(float v) {
    v += __shfl_xor(v, 16); v += __shfl_xor(v, 8); v += __shfl_xor(v, 4);
    v += __shfl_xor(v, 2);  v += __shfl_xor(v, 1);
    return v;
}
__device__ __forceinline__ float softplusf(float x) {
    return fmaxf(x, 0.f) + log1pf(expf(-fabsf(x)));
}
__device__ __forceinline__ void stout(void* o, long long idx, float v, bool f32) {
    if (f32) ((float*)o)[idx] = v;
    else     ((u16*)o)[idx]   = f2bf(v);
}

// ---------------------------------------------------------------------------
// dtype detection: bf16 data -> low u16 of each dword has a sane bf16 exponent
// (~64/64 votes); fp32 data -> low u16 is mantissa noise (~10/64 votes).
// ---------------------------------------------------------------------------
__global__ void k_detect(const u32* __restrict__ xw, int* __restrict__ flag)
{
    int t = threadIdx.x;            // 64 threads
    u32 wrd = xw[t];
    u32 e = (wrd >> 7) & 0xFF;      // exponent field of low u16 as bf16
    bool plaus = (e >= 0x60 && e <= 0x85);
    unsigned long long b = __ballot(plaus);
    if (t == 0) flag[0] = (__popcll(b) < 32) ? 1 : 0;   // 1 => fp32 storage
}

// ---------------------------------------------------------------------------
// GEMM: h = x @ W  (50000x128 @ 128x128), dual-dtype loads, bf16 h out.
// wave handles 4 nodes; lane computes channels c=lane and c=lane+64.
// W^T staged in LDS (bf16) with 16B-chunk XOR swizzle.
// Epilogue: per-node-per-head attention scalars ai/aj via shfl reductions.
// ---------------------------------------------------------------------------
__global__ __launch_bounds__(256) void k_gemm(
    const void* __restrict__ xv, const void* __restrict__ wv_,
    const void* __restrict__ attv, const int* __restrict__ flag,
    u16* __restrict__ hb, float* __restrict__ ai, float* __restrict__ aj)
{
    __shared__ __align__(16) u16 wt[128 * 128];
    __shared__ __align__(16) float xs[4][4][128];
    const int tid = threadIdx.x;
    const bool f32 = flag[0] != 0;

    if (f32) {
        const float* w = (const float*)wv_;
        const int k0 = tid >> 5;            // 0..7
        const int cb = (tid & 31) << 2;     // 0,4,...,124
        for (int k = k0; k < 128; k += 8) {
            float4 u = *(const float4*)(w + k * 128 + cb);
            const int chunkbase = k >> 3, kin = k & 7;
            float vv[4] = {u.x, u.y, u.z, u.w};
#pragma unroll
            for (int j = 0; j < 4; j++) {
                int c = cb + j;
                int chunk = chunkbase ^ (c & 15);
                wt[c * 128 + chunk * 8 + kin] = f2bf(vv[j]);
            }
        }
    } else {
        const u16* w = (const u16*)wv_;
        const int k0 = tid >> 4;            // 0..15
        const int cb = (tid & 15) << 3;     // 0,8,...,120
        for (int k = k0; k < 128; k += 16) {
            uint4 u = *(const uint4*)(w + k * 128 + cb);
            u16 v[8];
            v[0] = (u16)(u.x & 0xFFFF); v[1] = (u16)(u.x >> 16);
            v[2] = (u16)(u.y & 0xFFFF); v[3] = (u16)(u.y >> 16);
            v[4] = (u16)(u.z & 0xFFFF); v[5] = (u16)(u.z >> 16);
            v[6] = (u16)(u.w & 0xFFFF); v[7] = (u16)(u.w >> 16);
            const int chunkbase = k >> 3, kin = k & 7;
#pragma unroll
            for (int j = 0; j < 8; j++) {
                int c = cb + j;
                int chunk = chunkbase ^ (c & 15);
                wt[c * 128 + chunk * 8 + kin] = v[j];
            }
        }
    }

    const int wv = tid >> 6, lane = tid & 63;
    const int nb = blockIdx.x * 16 + wv * 4;
#pragma unroll
    for (int i = 0; i < 4; i++) {
        int n = nb + i;
        float vx = 0.f, vy = 0.f;
        if (n < NN) {
            if (f32) {
                float2 u = *(const float2*)((const float*)xv + (size_t)n * 128 + lane * 2);
                vx = u.x; vy = u.y;
            } else {
                u32 u = *(const u32*)((const u16*)xv + (size_t)n * 128 + lane * 2);
                vx = lo16(u); vy = hi16(u);
            }
        }
        xs[wv][i][lane * 2]     = vx;
        xs[wv][i][lane * 2 + 1] = vy;
    }
    __syncthreads();

    float acc[4][2] = {};
    const uint4* wt4 = (const uint4*)wt;
    const int sw = lane & 15;
#pragma unroll 4
    for (int kk = 0; kk < 16; kk++) {
        uint4 u0 = wt4[lane * 16 + (kk ^ sw)];
        uint4 u1 = wt4[(lane + 64) * 16 + (kk ^ sw)];
        float w0f[8], w1f[8];
        w0f[0] = lo16(u0.x); w0f[1] = hi16(u0.x);
        w0f[2] = lo16(u0.y); w0f[3] = hi16(u0.y);
        w0f[4] = lo16(u0.z); w0f[5] = hi16(u0.z);
        w0f[6] = lo16(u0.w); w0f[7] = hi16(u0.w);
        w1f[0] = lo16(u1.x); w1f[1] = hi16(u1.x);
        w1f[2] = lo16(u1.y); w1f[3] = hi16(u1.y);
        w1f[4] = lo16(u1.z); w1f[5] = hi16(u1.z);
        w1f[6] = lo16(u1.w); w1f[7] = hi16(u1.w);
#pragma unroll
        for (int i = 0; i < 4; i++) {
            const float* xp = &xs[wv][i][kk * 8];
            float4 xa = *(const float4*)(xp);
            float4 xb = *(const float4*)(xp + 4);
            acc[i][0] += xa.x * w0f[0] + xa.y * w0f[1] + xa.z * w0f[2] + xa.w * w0f[3]
                       + xb.x * w0f[4] + xb.y * w0f[5] + xb.z * w0f[6] + xb.w * w0f[7];
            acc[i][1] += xa.x * w1f[0] + xa.y * w1f[1] + xa.z * w1f[2] + xa.w * w1f[3]
                       + xb.x * w1f[4] + xb.y * w1f[5] + xb.z * w1f[6] + xb.w * w1f[7];
        }
    }

    // epilogue: store h (bf16), compute ai/aj
    const int hl = lane >> 5, j = lane & 31;
    float atti0, attj0, atti1, attj1;
    if (f32) {
        const float* att = (const float*)attv;
        atti0 = att[hl * 64 + j];        attj0 = att[hl * 64 + 32 + j];
        atti1 = att[(hl + 2) * 64 + j];  attj1 = att[(hl + 2) * 64 + 32 + j];
    } else {
        const u16* att = (const u16*)attv;
        atti0 = bf2f(att[hl * 64 + j]);        attj0 = bf2f(att[hl * 64 + 32 + j]);
        atti1 = bf2f(att[(hl + 2) * 64 + j]);  attj1 = bf2f(att[(hl + 2) * 64 + 32 + j]);
    }
#pragma unroll
    for (int i = 0; i < 4; i++) {
        int n = nb + i;
        if (n >= NN) break;
        hb[(size_t)n * 128 + lane]      = f2bf(acc[i][0]);
        hb[(size_t)n * 128 + 64 + lane] = f2bf(acc[i][1]);
        float r0 = red32(acc[i][0] * atti0);
        float r1 = red32(acc[i][0] * attj0);
        float r2 = red32(acc[i][1] * atti1);
        float r3 = red32(acc[i][1] * attj1);
        if (j == 0) {
            ai[n * 4 + hl]     = r0;
            aj[n * 4 + hl]     = r1;
            ai[n * 4 + 2 + hl] = r2;
            aj[n * 4 + 2 + hl] = r3;
        }
    }
}

// ---------------------------------------------------------------------------
// CSR build: count, scan, fill (permute src indices into dst-buckets)
// ---------------------------------------------------------------------------
__global__ __launch_bounds__(256) void k_count(const int* __restrict__ dst,
                                               int* __restrict__ counts, int E)
{
    int e = blockIdx.x * 256 + threadIdx.x;
    if (e < E) atomicAdd(&counts[dst[e]], 1);
}

__global__ __launch_bounds__(1024) void k_scan(const int* __restrict__ counts,
                                               int* __restrict__ row_start)
{
    __shared__ int part[1024];
    const int t = threadIdx.x;
    const int CH = (NN + 1023) / 1024;
    const int base = t * CH;
    int s = 0;
    for (int i = 0; i < CH; i++) {
        int idx = base + i;
        if (idx < NN) s += counts[idx];
    }
    part[t] = s;
    __syncthreads();
    for (int off = 1; off < 1024; off <<= 1) {
        int u = (t >= off) ? part[t - off] : 0;
        __syncthreads();
        part[t] += u;
        __syncthreads();
    }
    int run = part[t] - s;
    for (int i = 0; i < CH; i++) {
        int idx = base + i;
        if (idx < NN) { row_start[idx] = run; run += counts[idx]; }
    }
    if (t == 1023) row_start[NN] = run;
}

__global__ __launch_bounds__(256) void k_fill(
    const int* __restrict__ src, const int* __restrict__ dst,
    const int* __restrict__ row_start, int* __restrict__ cursor,
    int* __restrict__ perm_src, int E)
{
    int e = blockIdx.x * 256 + threadIdx.x;
    if (e >= E) return;
    int d = dst[e];
    int pos = row_start[d] + atomicAdd(&cursor[d], 1);
    perm_src[pos] = src[e];
}

// ---------------------------------------------------------------------------
// Aggregation + finalize: 32 threads/node, lane l -> channels 4l..4l+3,
// head = l>>3. Alpha recomputed from ai/aj (L2-resident); two-pass softmax.
// ---------------------------------------------------------------------------
__global__ __launch_bounds__(256) void k_agg(
    const int* __restrict__ row_start, const int* __restrict__ perm_src,
    const float* __restrict__ ai, const float* __restrict__ aj,
    const u16* __restrict__ hb, const void* __restrict__ biasv,
    const int* __restrict__ flag, void* __restrict__ outv)
{
    const int t = blockIdx.x * 256 + threadIdx.x;
    const int node = t >> 5;
    if (node >= NN) return;
    const bool f32 = flag[0] != 0;
    const int l = t & 31;
    const int head = l >> 3;
    const int c4 = (l & 7) << 2;

    const int rs = row_start[node];
    const int re = row_start[node + 1];
    const float ain = ai[node * 4 + head];

    float m = -1e30f;
    for (int i = rs; i < re; i++) {
        int s = perm_src[i];
        float a = aj[s * 4 + head] + ain;
        a = a > 0.f ? a : NEG_SLOPE * a;
        m = fmaxf(m, a);
    }

    float dsum = 0.f, ax = 0.f, ay = 0.f, az = 0.f, aw = 0.f;
    for (int i = rs; i < re; i++) {
        int s = perm_src[i];
        float a = aj[s * 4 + head] + ain;
        a = a > 0.f ? a : NEG_SLOPE * a;
        float ev = __expf(a - m);
        dsum += ev;
        uint2 hv = *(const uint2*)(hb + (size_t)s * 128 + l * 4);
        ax += ev * lo16(hv.x); ay += ev * hi16(hv.x);
        az += ev * lo16(hv.y); aw += ev * hi16(hv.y);
    }
    const float inv = 1.f / (dsum + 1e-16f);
    const int cb = head * 32 + c4;
    float b0, b1, b2, b3;
    if (f32) {
        const float* bias = (const float*)biasv;
        b0 = bias[cb]; b1 = bias[cb + 1]; b2 = bias[cb + 2]; b3 = bias[cb + 3];
    } else {
        const u16* bias = (const u16*)biasv;
        b0 = bf2f(bias[cb]); b1 = bf2f(bias[cb + 1]);
        b2 = bf2f(bias[cb + 2]); b3 = bf2f(bias[cb + 3]);
    }
    float vx = ax * inv + b0;
    float vy = ay * inv + b1;
    float vz = az * inv + b2;
    float vw = aw * inv + b3;

    float part;
    if (c4 < 16) {
        part = 0.5f * (vx * vx + vy * vy + vz * vz + vw * vw);
        long long o = (long long)node * 64 + head * 16 + c4;
        stout(outv, o + 0, vx, f32); stout(outv, o + 1, vy, f32);
        stout(outv, o + 2, vz, f32); stout(outv, o + 3, vw, f32);
        long long om = (long long)MEAN_OFF + o;
        stout(outv, om + 0, vx, f32); stout(outv, om + 1, vy, f32);
        stout(outv, om + 2, vz, f32); stout(outv, om + 3, vw, f32);
    } else {
        float s0 = softplusf(vx - 5.f) + 1e-10f;
        float s1 = softplusf(vy - 5.f) + 1e-10f;
        float s2 = softplusf(vz - 5.f) + 1e-10f;
        float s3 = softplusf(vw - 5.f) + 1e-10f;
        part = (-logf(s0) + 0.5f * s0 * s0 - 0.5f)
             + (-logf(s1) + 0.5f * s1 * s1 - 0.5f)
             + (-logf(s2) + 0.5f * s2 * s2 - 0.5f)
             + (-logf(s3) + 0.5f * s3 * s3 - 0.5f);
        long long os = (long long)STD_OFF + (long long)node * 64 + head * 16 + (c4 - 16);
        stout(outv, os + 0, s0, f32); stout(outv, os + 1, s1, f32);
        stout(outv, os + 2, s2, f32); stout(outv, os + 3, s3, f32);
    }
    part = red32(part);
    if (l == 0) stout(outv, (long long)IXZ_OFF + node, part * 0.25f, f32);
    if (t == 0) stout(outv, (long long)SKL_OFF, 0.f, f32);
}

// ---------------------------------------------------------------------------
extern "C" void kernel_launch(void* const* d_in, const int* in_sizes, int n_in,
                              void* d_out, int out_size, void* d_ws, size_t ws_size,
                              hipStream_t stream)
{
    const void* x    = d_in[0];
    const int*  ei   = (const int*)d_in[1];
    const void* w    = d_in[2];
    const void* att  = d_in[3];
    const void* bias = d_in[4];

    const int E = in_sizes[1] / 2;
    const int* src = ei;
    const int* dst = ei + E;

    // workspace layout (~17.6 MB)
    u16*   hb        = (u16*)d_ws;                    // NN*128 bf16
    float* ai        = (float*)(hb + (size_t)NN * 128);
    float* aj        = ai + NN * 4;
    int*   perm_src  = (int*)(aj + NN * 4);           // E
    int*   row_start = perm_src + E;                  // NN+1
    int*   counts    = row_start + NN + 1;            // NN
    int*   cursor    = counts + NN;                   // NN
    int*   flag      = cursor + NN;                   // 1

    k_detect<<<1, 64, 0, stream>>>((const u32*)x, flag);
    hipMemsetAsync(counts, 0, sizeof(int) * 2 * NN, stream);
    k_gemm<<<(NN + 15) / 16, 256, 0, stream>>>(x, w, att, flag, hb, ai, aj);
    k_count<<<(E + 255) / 256, 256, 0, stream>>>(dst, counts, E);
    k_scan<<<1, 1024, 0, stream>>>(counts, row_start);
    k_fill<<<(E + 255) / 256, 256, 0, stream>>>(src, dst, row_start, cursor,
                                                perm_src, E);
    k_agg<<<(NN * 32 + 255) / 256, 256, 0, stream>>>(row_start, perm_src, ai, aj,
                                                     hb, bias, flag, d_out);
}

// Round 3
// 305.353 us; speedup vs baseline: 1.2898x; 1.2898x over previous
//
#include <hip/hip_runtime.h>
#include <stdint.h>

#define NN 50000
#define NB 196              // ceil(NN/256)
#define NEG_SLOPE 0.2f

// output layout (element offsets)
#define IXZ_OFF    (NN * 64)
#define SKL_OFF    (NN * 64 + NN)
#define MEAN_OFF   (NN * 64 + NN + 1)
#define STD_OFF    (MEAN_OFF + NN * 64)

typedef unsigned int u32;
typedef unsigned short u16;

__device__ __forceinline__ float bf2f(u16 s) { return __uint_as_float(((u32)s) << 16); }
__device__ __forceinline__ u16 f2bf(float f) {
    u32 u = __float_as_uint(f);
    u += 0x7FFFu + ((u >> 16) & 1u);   // RNE
    return (u16)(u >> 16);
}
__device__ __forceinline__ float lo16(u32 u) { return __uint_as_float(u << 16); }
__device__ __forceinline__ float hi16(u32 u) { return __uint_as_float(u & 0xFFFF0000u); }
__device__ __forceinline__ float red32(float v) {
    v += __shfl_xor(v, 16); v += __shfl_xor(v, 8); v += __shfl_xor(v, 4);
    v += __shfl_xor(v, 2);  v += __shfl_xor(v, 1);
    return v;
}
__device__ __forceinline__ float softplusf(float x) {
    return fmaxf(x, 0.f) + log1pf(expf(-fabsf(x)));
}
__device__ __forceinline__ void stout(void* o, long long idx, float v, bool f32) {
    if (f32) ((float*)o)[idx] = v;
    else     ((u16*)o)[idx]   = f2bf(v);
}
__device__ __forceinline__ int wscan_incl(int v, int lane) {
#pragma unroll
    for (int off = 1; off < 64; off <<= 1) {
        int u = __shfl_up(v, off);
        if (lane >= off) v += u;
    }
    return v;
}

// ---------------------------------------------------------------------------
// dtype detection: bf16 data -> low u16 of each dword has a sane bf16 exponent
// ---------------------------------------------------------------------------
__global__ void k_detect(const u32* __restrict__ xw, int* __restrict__ flag)
{
    int t = threadIdx.x;            // 64 threads
    u32 wrd = xw[t];
    u32 e = (wrd >> 7) & 0xFF;
    bool plaus = (e >= 0x60 && e <= 0x85);
    unsigned long long b = __ballot(plaus);
    if (t == 0) flag[0] = (__popcll(b) < 32) ? 1 : 0;   // 1 => fp32 storage
}

// ---------------------------------------------------------------------------
// GEMM: h = x @ W  (50000x128 @ 128x128), dual-dtype loads, bf16 h out.
// wave handles 4 nodes; lane computes channels c=lane and c=lane+64.
// W^T staged in LDS (bf16) with 16B-chunk XOR swizzle.
// Epilogue: per-node-per-head attention scalars ai/aj via shfl reductions.
// ---------------------------------------------------------------------------
__global__ __launch_bounds__(256) void k_gemm(
    const void* __restrict__ xv, const void* __restrict__ wv_,
    const void* __restrict__ attv, const int* __restrict__ flag,
    u16* __restrict__ hb, float* __restrict__ ai, float* __restrict__ aj)
{
    __shared__ __align__(16) u16 wt[128 * 128];
    __shared__ __align__(16) float xs[4][4][128];
    const int tid = threadIdx.x;
    const bool f32 = flag[0] != 0;

    if (f32) {
        const float* w = (const float*)wv_;
        const int k0 = tid >> 5;
        const int cb = (tid & 31) << 2;
        for (int k = k0; k < 128; k += 8) {
            float4 u = *(const float4*)(w + k * 128 + cb);
            const int chunkbase = k >> 3, kin = k & 7;
            float vv[4] = {u.x, u.y, u.z, u.w};
#pragma unroll
            for (int j = 0; j < 4; j++) {
                int c = cb + j;
                int chunk = chunkbase ^ (c & 15);
                wt[c * 128 + chunk * 8 + kin] = f2bf(vv[j]);
            }
        }
    } else {
        const u16* w = (const u16*)wv_;
        const int k0 = tid >> 4;
        const int cb = (tid & 15) << 3;
        for (int k = k0; k < 128; k += 16) {
            uint4 u = *(const uint4*)(w + k * 128 + cb);
            u16 v[8];
            v[0] = (u16)(u.x & 0xFFFF); v[1] = (u16)(u.x >> 16);
            v[2] = (u16)(u.y & 0xFFFF); v[3] = (u16)(u.y >> 16);
            v[4] = (u16)(u.z & 0xFFFF); v[5] = (u16)(u.z >> 16);
            v[6] = (u16)(u.w & 0xFFFF); v[7] = (u16)(u.w >> 16);
            const int chunkbase = k >> 3, kin = k & 7;
#pragma unroll
            for (int j = 0; j < 8; j++) {
                int c = cb + j;
                int chunk = chunkbase ^ (c & 15);
                wt[c * 128 + chunk * 8 + kin] = v[j];
            }
        }
    }

    const int wv = tid >> 6, lane = tid & 63;
    const int nb = blockIdx.x * 16 + wv * 4;
#pragma unroll
    for (int i = 0; i < 4; i++) {
        int n = nb + i;
        float vx = 0.f, vy = 0.f;
        if (n < NN) {
            if (f32) {
                float2 u = *(const float2*)((const float*)xv + (size_t)n * 128 + lane * 2);
                vx = u.x; vy = u.y;
            } else {
                u32 u = *(const u32*)((const u16*)xv + (size_t)n * 128 + lane * 2);
                vx = lo16(u); vy = hi16(u);
            }
        }
        xs[wv][i][lane * 2]     = vx;
        xs[wv][i][lane * 2 + 1] = vy;
    }
    __syncthreads();

    float acc[4][2] = {};
    const uint4* wt4 = (const uint4*)wt;
    const int sw = lane & 15;
#pragma unroll 4
    for (int kk = 0; kk < 16; kk++) {
        uint4 u0 = wt4[lane * 16 + (kk ^ sw)];
        uint4 u1 = wt4[(lane + 64) * 16 + (kk ^ sw)];
        float w0f[8], w1f[8];
        w0f[0] = lo16(u0.x); w0f[1] = hi16(u0.x);
        w0f[2] = lo16(u0.y); w0f[3] = hi16(u0.y);
        w0f[4] = lo16(u0.z); w0f[5] = hi16(u0.z);
        w0f[6] = lo16(u0.w); w0f[7] = hi16(u0.w);
        w1f[0] = lo16(u1.x); w1f[1] = hi16(u1.x);
        w1f[2] = lo16(u1.y); w1f[3] = hi16(u1.y);
        w1f[4] = lo16(u1.z); w1f[5] = hi16(u1.z);
        w1f[6] = lo16(u1.w); w1f[7] = hi16(u1.w);
#pragma unroll
        for (int i = 0; i < 4; i++) {
            const float* xp = &xs[wv][i][kk * 8];
            float4 xa = *(const float4*)(xp);
            float4 xb = *(const float4*)(xp + 4);
            acc[i][0] += xa.x * w0f[0] + xa.y * w0f[1] + xa.z * w0f[2] + xa.w * w0f[3]
                       + xb.x * w0f[4] + xb.y * w0f[5] + xb.z * w0f[6] + xb.w * w0f[7];
            acc[i][1] += xa.x * w1f[0] + xa.y * w1f[1] + xa.z * w1f[2] + xa.w * w1f[3]
                       + xb.x * w1f[4] + xb.y * w1f[5] + xb.z * w1f[6] + xb.w * w1f[7];
        }
    }

    const int hl = lane >> 5, j = lane & 31;
    float atti0, attj0, atti1, attj1;
    if (f32) {
        const float* att = (const float*)attv;
        atti0 = att[hl * 64 + j];        attj0 = att[hl * 64 + 32 + j];
        atti1 = att[(hl + 2) * 64 + j];  attj1 = att[(hl + 2) * 64 + 32 + j];
    } else {
        const u16* att = (const u16*)attv;
        atti0 = bf2f(att[hl * 64 + j]);        attj0 = bf2f(att[hl * 64 + 32 + j]);
        atti1 = bf2f(att[(hl + 2) * 64 + j]);  attj1 = bf2f(att[(hl + 2) * 64 + 32 + j]);
    }
#pragma unroll
    for (int i = 0; i < 4; i++) {
        int n = nb + i;
        if (n >= NN) break;
        hb[(size_t)n * 128 + lane]      = f2bf(acc[i][0]);
        hb[(size_t)n * 128 + 64 + lane] = f2bf(acc[i][1]);
        float r0 = red32(acc[i][0] * atti0);
        float r1 = red32(acc[i][0] * attj0);
        float r2 = red32(acc[i][1] * atti1);
        float r3 = red32(acc[i][1] * attj1);
        if (j == 0) {
            ai[n * 4 + hl]     = r0;
            aj[n * 4 + hl]     = r1;
            ai[n * 4 + 2 + hl] = r2;
            aj[n * 4 + 2 + hl] = r3;
        }
    }
}

// ---------------------------------------------------------------------------
// CSR build: count, hierarchical scan (2 levels), fill
// ---------------------------------------------------------------------------
__global__ __launch_bounds__(256) void k_count(const int* __restrict__ dst,
                                               int* __restrict__ counts, int E)
{
    int e = blockIdx.x * 256 + threadIdx.x;
    if (e < E) atomicAdd(&counts[dst[e]], 1);
}

// per-256-chunk exclusive prefix (lexcl) + chunk sums
__global__ __launch_bounds__(256) void k_scan1(const int* __restrict__ counts,
                                               int* __restrict__ lexcl,
                                               int* __restrict__ blocksum)
{
    __shared__ int wsum[4];
    const int t = threadIdx.x, lane = t & 63, wv = t >> 6;
    const int i = blockIdx.x * 256 + t;
    int c = (i < NN) ? counts[i] : 0;
    int inc = wscan_incl(c, lane);
    if (lane == 63) wsum[wv] = inc;
    __syncthreads();
    int add = 0;
#pragma unroll
    for (int k = 0; k < 3; k++) if (k < wv) add += wsum[k];
    inc += add;
    if (i < NN) lexcl[i] = inc - c;
    if (t == 255) blocksum[blockIdx.x] = inc;
}

// exclusive prefix of the NB chunk sums
__global__ __launch_bounds__(256) void k_scan2(const int* __restrict__ blocksum,
                                               int* __restrict__ blockoff)
{
    __shared__ int wsum[4];
    const int t = threadIdx.x, lane = t & 63, wv = t >> 6;
    int c = (t < NB) ? blocksum[t] : 0;
    int inc = wscan_incl(c, lane);
    if (lane == 63) wsum[wv] = inc;
    __syncthreads();
    int add = 0;
#pragma unroll
    for (int k = 0; k < 3; k++) if (k < wv) add += wsum[k];
    inc += add;
    if (t < NB) blockoff[t] = inc - c;
}

__global__ __launch_bounds__(256) void k_fill(
    const int* __restrict__ src, const int* __restrict__ dst,
    const int* __restrict__ lexcl, const int* __restrict__ blockoff,
    int* __restrict__ cursor, int* __restrict__ perm_src, int E)
{
    int e = blockIdx.x * 256 + threadIdx.x;
    if (e >= E) return;
    int d = dst[e];
    int pos = blockoff[d >> 8] + lexcl[d] + atomicAdd(&cursor[d], 1);
    perm_src[pos] = src[e];
}

// ---------------------------------------------------------------------------
// Aggregation + finalize: 32 threads/node, lane l -> channels 4l..4l+3,
// head = l>>3. Alpha recomputed from ai/aj (L2-resident); two-pass softmax.
// ---------------------------------------------------------------------------
__global__ __launch_bounds__(256) void k_agg(
    const int* __restrict__ lexcl, const int* __restrict__ blockoff,
    const int* __restrict__ counts, const int* __restrict__ perm_src,
    const float* __restrict__ ai, const float* __restrict__ aj,
    const u16* __restrict__ hb, const void* __restrict__ biasv,
    const int* __restrict__ flag, void* __restrict__ outv)
{
    const int t = blockIdx.x * 256 + threadIdx.x;
    const int node = t >> 5;
    if (node >= NN) return;
    const bool f32 = flag[0] != 0;
    const int l = t & 31;
    const int head = l >> 3;
    const int c4 = (l & 7) << 2;

    const int rs = blockoff[node >> 8] + lexcl[node];
    const int re = rs + counts[node];
    const float ain = ai[node * 4 + head];

    float m = -1e30f;
    for (int i = rs; i < re; i++) {
        int s = perm_src[i];
        float a = aj[s * 4 + head] + ain;
        a = a > 0.f ? a : NEG_SLOPE * a;
        m = fmaxf(m, a);
    }

    float dsum = 0.f, ax = 0.f, ay = 0.f, az = 0.f, aw = 0.f;
    for (int i = rs; i < re; i++) {
        int s = perm_src[i];
        float a = aj[s * 4 + head] + ain;
        a = a > 0.f ? a : NEG_SLOPE * a;
        float ev = __expf(a - m);
        dsum += ev;
        uint2 hv = *(const uint2*)(hb + (size_t)s * 128 + l * 4);
        ax += ev * lo16(hv.x); ay += ev * hi16(hv.x);
        az += ev * lo16(hv.y); aw += ev * hi16(hv.y);
    }
    const float inv = 1.f / (dsum + 1e-16f);
    const int cb = head * 32 + c4;
    float b0, b1, b2, b3;
    if (f32) {
        const float* bias = (const float*)biasv;
        b0 = bias[cb]; b1 = bias[cb + 1]; b2 = bias[cb + 2]; b3 = bias[cb + 3];
    } else {
        const u16* bias = (const u16*)biasv;
        b0 = bf2f(bias[cb]); b1 = bf2f(bias[cb + 1]);
        b2 = bf2f(bias[cb + 2]); b3 = bf2f(bias[cb + 3]);
    }
    float vx = ax * inv + b0;
    float vy = ay * inv + b1;
    float vz = az * inv + b2;
    float vw = aw * inv + b3;

    float part;
    if (c4 < 16) {
        part = 0.5f * (vx * vx + vy * vy + vz * vz + vw * vw);
        long long o = (long long)node * 64 + head * 16 + c4;
        stout(outv, o + 0, vx, f32); stout(outv, o + 1, vy, f32);
        stout(outv, o + 2, vz, f32); stout(outv, o + 3, vw, f32);
        long long om = (long long)MEAN_OFF + o;
        stout(outv, om + 0, vx, f32); stout(outv, om + 1, vy, f32);
        stout(outv, om + 2, vz, f32); stout(outv, om + 3, vw, f32);
    } else {
        float s0 = softplusf(vx - 5.f) + 1e-10f;
        float s1 = softplusf(vy - 5.f) + 1e-10f;
        float s2 = softplusf(vz - 5.f) + 1e-10f;
        float s3 = softplusf(vw - 5.f) + 1e-10f;
        part = (-logf(s0) + 0.5f * s0 * s0 - 0.5f)
             + (-logf(s1) + 0.5f * s1 * s1 - 0.5f)
             + (-logf(s2) + 0.5f * s2 * s2 - 0.5f)
             + (-logf(s3) + 0.5f * s3 * s3 - 0.5f);
        long long os = (long long)STD_OFF + (long long)node * 64 + head * 16 + (c4 - 16);
        stout(outv, os + 0, s0, f32); stout(outv, os + 1, s1, f32);
        stout(outv, os + 2, s2, f32); stout(outv, os + 3, s3, f32);
    }
    part = red32(part);
    if (l == 0) stout(outv, (long long)IXZ_OFF + node, part * 0.25f, f32);
    if (t == 0) stout(outv, (long long)SKL_OFF, 0.f, f32);
}

// ---------------------------------------------------------------------------
extern "C" void kernel_launch(void* const* d_in, const int* in_sizes, int n_in,
                              void* d_out, int out_size, void* d_ws, size_t ws_size,
                              hipStream_t stream)
{
    const void* x    = d_in[0];
    const int*  ei   = (const int*)d_in[1];
    const void* w    = d_in[2];
    const void* att  = d_in[3];
    const void* bias = d_in[4];

    const int E = in_sizes[1] / 2;
    const int* src = ei;
    const int* dst = ei + E;

    // workspace layout (~17.8 MB)
    u16*   hb        = (u16*)d_ws;                    // NN*128 bf16
    float* ai        = (float*)(hb + (size_t)NN * 128);
    float* aj        = ai + NN * 4;
    int*   perm_src  = (int*)(aj + NN * 4);           // E
    int*   counts    = perm_src + E;                  // NN
    int*   cursor    = counts + NN;                   // NN
    int*   lexcl     = cursor + NN;                   // NN
    int*   blocksum  = lexcl + NN;                    // NB
    int*   blockoff  = blocksum + NB;                 // NB
    int*   flag      = blockoff + NB;                 // 1

    k_detect<<<1, 64, 0, stream>>>((const u32*)x, flag);
    hipMemsetAsync(counts, 0, sizeof(int) * 2 * NN, stream);
    k_gemm<<<(NN + 15) / 16, 256, 0, stream>>>(x, w, att, flag, hb, ai, aj);
    k_count<<<(E + 255) / 256, 256, 0, stream>>>(dst, counts, E);
    k_scan1<<<NB, 256, 0, stream>>>(counts, lexcl, blocksum);
    k_scan2<<<1, 256, 0, stream>>>(blocksum, blockoff);
    k_fill<<<(E + 255) / 256, 256, 0, stream>>>(src, dst, lexcl, blockoff,
                                                cursor, perm_src, E);
    k_agg<<<(NN * 32 + 255) / 256, 256, 0, stream>>>(lexcl, blockoff, counts,
                                                     perm_src, ai, aj, hb, bias,
                                                     flag, d_out);
}

// Round 4
// 247.645 us; speedup vs baseline: 1.5903x; 1.2330x over previous
//
#include <hip/hip_runtime.h>
#include <stdint.h>

#define NN 50000
#define NB 196              // ceil(NN/256)
#define NEG_SLOPE 0.2f
#define WTS 136             // padded W^T row stride (u16): 128 + 8 -> conflict-spread b128

// output layout (element offsets)
#define IXZ_OFF    (NN * 64)
#define SKL_OFF    (NN * 64 + NN)
#define MEAN_OFF   (NN * 64 + NN + 1)
#define STD_OFF    (MEAN_OFF + NN * 64)

typedef unsigned int u32;
typedef unsigned short u16;
typedef __attribute__((ext_vector_type(8))) short short8;   // 8 bf16 = 4 VGPRs (MFMA A/B frag)
typedef __attribute__((ext_vector_type(4))) float f32x4;    // MFMA C/D frag

__device__ __forceinline__ float bf2f(u16 s) { return __uint_as_float(((u32)s) << 16); }
__device__ __forceinline__ u16 f2bf(float f) {
    u32 u = __float_as_uint(f);
    u += 0x7FFFu + ((u >> 16) & 1u);   // RNE
    return (u16)(u >> 16);
}
__device__ __forceinline__ float lo16(u32 u) { return __uint_as_float(u << 16); }
__device__ __forceinline__ float hi16(u32 u) { return __uint_as_float(u & 0xFFFF0000u); }
__device__ __forceinline__ float red32(float v) {
    v += __shfl_xor(v, 16); v += __shfl_xor(v, 8); v += __shfl_xor(v, 4);
    v += __shfl_xor(v, 2);  v += __shfl_xor(v, 1);
    return v;
}
__device__ __forceinline__ float softplusf(float x) {
    return fmaxf(x, 0.f) + log1pf(expf(-fabsf(x)));
}
__device__ __forceinline__ void stout(void* o, long long idx, float v, bool f32) {
    if (f32) ((float*)o)[idx] = v;
    else     ((u16*)o)[idx]   = f2bf(v);
}
__device__ __forceinline__ int wscan_incl(int v, int lane) {
#pragma unroll
    for (int off = 1; off < 64; off <<= 1) {
        int u = __shfl_up(v, off);
        if (lane >= off) v += u;
    }
    return v;
}

// ---------------------------------------------------------------------------
// dtype detection: bf16 data -> low u16 of each dword has a sane bf16 exponent
// ---------------------------------------------------------------------------
__global__ void k_detect(const u32* __restrict__ xw, int* __restrict__ flag)
{
    int t = threadIdx.x;            // 64 threads
    u32 wrd = xw[t];
    u32 e = (wrd >> 7) & 0xFF;
    bool plaus = (e >= 0x60 && e <= 0x85);
    unsigned long long b = __ballot(plaus);
    if (t == 0) flag[0] = (__popcll(b) < 32) ? 1 : 0;   // 1 => fp32 storage
}

// ---------------------------------------------------------------------------
// k_wt: W (k,c) -> global padded W^T image (bf16), rows = channel, stride WTS.
// 8 blocks x 256 thr; block b handles k in [16b, 16b+16). One-time ~2 us.
// ---------------------------------------------------------------------------
__global__ __launch_bounds__(256) void k_wt(const void* __restrict__ wv_,
                                            const int* __restrict__ flag,
                                            u16* __restrict__ wtg)
{
    const int t = threadIdx.x;
    const int k = blockIdx.x * 16 + (t >> 4);
    const int cq = t & 15;          // 8-channel group
    const bool f32 = flag[0] != 0;
    u16 v[8];
    if (f32) {
        const float* w = (const float*)wv_;
        float4 a = *(const float4*)(w + k * 128 + cq * 8);
        float4 b = *(const float4*)(w + k * 128 + cq * 8 + 4);
        v[0] = f2bf(a.x); v[1] = f2bf(a.y); v[2] = f2bf(a.z); v[3] = f2bf(a.w);
        v[4] = f2bf(b.x); v[5] = f2bf(b.y); v[6] = f2bf(b.z); v[7] = f2bf(b.w);
    } else {
        const u16* w = (const u16*)wv_;
        uint4 u = *(const uint4*)(w + k * 128 + cq * 8);
        v[0] = (u16)(u.x & 0xFFFF); v[1] = (u16)(u.x >> 16);
        v[2] = (u16)(u.y & 0xFFFF); v[3] = (u16)(u.y >> 16);
        v[4] = (u16)(u.z & 0xFFFF); v[5] = (u16)(u.z >> 16);
        v[6] = (u16)(u.w & 0xFFFF); v[7] = (u16)(u.w >> 16);
    }
#pragma unroll
    for (int j = 0; j < 8; j++)
        wtg[(cq * 8 + j) * WTS + k] = v[j];
}

// ---------------------------------------------------------------------------
// MFMA GEMM: h = x @ W. Wave = 16 nodes x 128 ch, 32x mfma_f32_16x16x32_bf16.
// A frags direct from global x; B frags from LDS W^T (linear-staged from wtg).
// Epilogue: ai/aj shfl-reduce from fp32 acc; hb repacked via LDS, uint4 stores.
// ---------------------------------------------------------------------------
__global__ __launch_bounds__(256) void k_gemm(
    const void* __restrict__ xv, const u16* __restrict__ wtg,
    const void* __restrict__ attv, const int* __restrict__ flag,
    u16* __restrict__ hb, float* __restrict__ ai, float* __restrict__ aj)
{
    __shared__ __align__(16) u16 ls[128 * WTS];   // 34816 B
    const int tid = threadIdx.x;
    const bool f32 = flag[0] != 0;

    // linear, conflict-free stage of padded W^T
    {
        uint4* d = (uint4*)ls;
        const uint4* s = (const uint4*)wtg;
        for (int i = tid; i < 128 * WTS / 8; i += 256) d[i] = s[i];
    }

    const int w = tid >> 6, L = tid & 63;
    const int q = L >> 4, c15 = L & 15;
    const int nb16 = blockIdx.x * 64 + w * 16;

    // A fragments: A[m=c15][k=q*8+j], ks = K/32 step
    short8 afr[4];
    {
        int nrow = nb16 + c15; if (nrow > NN - 1) nrow = NN - 1;
        if (f32) {
            const float* xp = (const float*)xv + (size_t)nrow * 128 + q * 8;
#pragma unroll
            for (int ks = 0; ks < 4; ks++) {
                float4 a = *(const float4*)(xp + ks * 32);
                float4 b = *(const float4*)(xp + ks * 32 + 4);
                union { short8 s; u16 e[8]; } u;
                u.e[0] = f2bf(a.x); u.e[1] = f2bf(a.y); u.e[2] = f2bf(a.z); u.e[3] = f2bf(a.w);
                u.e[4] = f2bf(b.x); u.e[5] = f2bf(b.y); u.e[6] = f2bf(b.z); u.e[7] = f2bf(b.w);
                afr[ks] = u.s;
            }
        } else {
            const u16* xp = (const u16*)xv + (size_t)nrow * 128 + q * 8;
#pragma unroll
            for (int ks = 0; ks < 4; ks++)
                afr[ks] = *(const short8*)(xp + ks * 32);
        }
    }
    __syncthreads();

    // 8 column tiles x 4 K-steps
    f32x4 acc[8];
#pragma unroll
    for (int t = 0; t < 8; t++) {
        acc[t] = (f32x4){0.f, 0.f, 0.f, 0.f};
        const u16* bp = ls + (16 * t + c15) * WTS + q * 8;
#pragma unroll
        for (int ks = 0; ks < 4; ks++) {
            short8 bfr = *(const short8*)(bp + ks * 32);
            acc[t] = __builtin_amdgcn_mfma_f32_16x16x32_bf16(afr[ks], bfr, acc[t], 0, 0, 0);
        }
    }

    // attention scalars: tile t -> head t>>1, within-head offset (t&1)*16 + c15
    float ati[8], atj[8];
#pragma unroll
    for (int t = 0; t < 8; t++) {
        int p = (t >> 1) * 64 + (t & 1) * 16 + c15;
        if (f32) {
            ati[t] = ((const float*)attv)[p];
            atj[t] = ((const float*)attv)[p + 32];
        } else {
            ati[t] = bf2f(((const u16*)attv)[p]);
            atj[t] = bf2f(((const u16*)attv)[p + 32]);
        }
    }
    // D layout: col = c15, row = q*4 + r  -> reduce over the 16 lanes of a q-group
#pragma unroll
    for (int r = 0; r < 4; r++) {
        int node = nb16 + q * 4 + r;
#pragma unroll
        for (int h = 0; h < 4; h++) {
            float pi = acc[2 * h][r] * ati[2 * h] + acc[2 * h + 1][r] * ati[2 * h + 1];
            float pj = acc[2 * h][r] * atj[2 * h] + acc[2 * h + 1][r] * atj[2 * h + 1];
            pi += __shfl_xor(pi, 1); pj += __shfl_xor(pj, 1);
            pi += __shfl_xor(pi, 2); pj += __shfl_xor(pj, 2);
            pi += __shfl_xor(pi, 4); pj += __shfl_xor(pj, 4);
            pi += __shfl_xor(pi, 8); pj += __shfl_xor(pj, 8);
            if (c15 == 0 && node < NN) { ai[node * 4 + h] = pi; aj[node * 4 + h] = pj; }
        }
    }

    // hb store: repack via wave-private LDS region, then coalesced uint4 stores
    __syncthreads();   // all waves done reading W^T before overwrite
    u16* myls = ls + w * 16 * WTS;
#pragma unroll
    for (int t = 0; t < 8; t++)
#pragma unroll
        for (int r = 0; r < 4; r++)
            myls[(q * 4 + r) * WTS + 16 * t + c15] = f2bf(acc[t][r]);
    // same-wave LDS write->read: DS pipe is in-order per wave
#pragma unroll
    for (int v = 0; v < 4; v++) {
        int idx = v * 64 + L;
        int nrow = idx >> 4, c8 = idx & 15;
        int node = nb16 + nrow;
        if (node < NN)
            *(uint4*)(hb + (size_t)node * 128 + c8 * 8) =
                *(const uint4*)(myls + nrow * WTS + c8 * 8);
    }
}

// ---------------------------------------------------------------------------
// CSR build: count, hierarchical scan (2 levels), fill
// ---------------------------------------------------------------------------
__global__ __launch_bounds__(256) void k_count(const int* __restrict__ dst,
                                               int* __restrict__ counts, int E)
{
    int e = blockIdx.x * 256 + threadIdx.x;
    if (e < E) atomicAdd(&counts[dst[e]], 1);
}

__global__ __launch_bounds__(256) void k_scan1(const int* __restrict__ counts,
                                               int* __restrict__ lexcl,
                                               int* __restrict__ blocksum)
{
    __shared__ int wsum[4];
    const int t = threadIdx.x, lane = t & 63, wv = t >> 6;
    const int i = blockIdx.x * 256 + t;
    int c = (i < NN) ? counts[i] : 0;
    int inc = wscan_incl(c, lane);
    if (lane == 63) wsum[wv] = inc;
    __syncthreads();
    int add = 0;
#pragma unroll
    for (int k = 0; k < 3; k++) if (k < wv) add += wsum[k];
    inc += add;
    if (i < NN) lexcl[i] = inc - c;
    if (t == 255) blocksum[blockIdx.x] = inc;
}

__global__ __launch_bounds__(256) void k_scan2(const int* __restrict__ blocksum,
                                               int* __restrict__ blockoff)
{
    __shared__ int wsum[4];
    const int t = threadIdx.x, lane = t & 63, wv = t >> 6;
    int c = (t < NB) ? blocksum[t] : 0;
    int inc = wscan_incl(c, lane);
    if (lane == 63) wsum[wv] = inc;
    __syncthreads();
    int add = 0;
#pragma unroll
    for (int k = 0; k < 3; k++) if (k < wv) add += wsum[k];
    inc += add;
    if (t < NB) blockoff[t] = inc - c;
}

__global__ __launch_bounds__(256) void k_fill(
    const int* __restrict__ src, const int* __restrict__ dst,
    const int* __restrict__ lexcl, const int* __restrict__ blockoff,
    int* __restrict__ cursor, int* __restrict__ perm_src, int E)
{
    int e = blockIdx.x * 256 + threadIdx.x;
    if (e >= E) return;
    int d = dst[e];
    int pos = blockoff[d >> 8] + lexcl[d] + atomicAdd(&cursor[d], 1);
    perm_src[pos] = src[e];
}

// ---------------------------------------------------------------------------
// Aggregation + finalize: 32 threads/node, lane l -> channels 4l..4l+3,
// head = l>>3. Alpha recomputed from ai/aj (L2-resident); two-pass softmax.
// ---------------------------------------------------------------------------
__global__ __launch_bounds__(256) void k_agg(
    const int* __restrict__ lexcl, const int* __restrict__ blockoff,
    const int* __restrict__ counts, const int* __restrict__ perm_src,
    const float* __restrict__ ai, const float* __restrict__ aj,
    const u16* __restrict__ hb, const void* __restrict__ biasv,
    const int* __restrict__ flag, void* __restrict__ outv)
{
    const int t = blockIdx.x * 256 + threadIdx.x;
    const int node = t >> 5;
    if (node >= NN) return;
    const bool f32 = flag[0] != 0;
    const int l = t & 31;
    const int head = l >> 3;
    const int c4 = (l & 7) << 2;

    const int rs = blockoff[node >> 8] + lexcl[node];
    const int re = rs + counts[node];
    const float ain = ai[node * 4 + head];

    float m = -1e30f;
    for (int i = rs; i < re; i++) {
        int s = perm_src[i];
        float a = aj[s * 4 + head] + ain;
        a = a > 0.f ? a : NEG_SLOPE * a;
        m = fmaxf(m, a);
    }

    float dsum = 0.f, ax = 0.f, ay = 0.f, az = 0.f, aw = 0.f;
    for (int i = rs; i < re; i++) {
        int s = perm_src[i];
        float a = aj[s * 4 + head] + ain;
        a = a > 0.f ? a : NEG_SLOPE * a;
        float ev = __expf(a - m);
        dsum += ev;
        uint2 hv = *(const uint2*)(hb + (size_t)s * 128 + l * 4);
        ax += ev * lo16(hv.x); ay += ev * hi16(hv.x);
        az += ev * lo16(hv.y); aw += ev * hi16(hv.y);
    }
    const float inv = 1.f / (dsum + 1e-16f);
    const int cb = head * 32 + c4;
    float b0, b1, b2, b3;
    if (f32) {
        const float* bias = (const float*)biasv;
        b0 = bias[cb]; b1 = bias[cb + 1]; b2 = bias[cb + 2]; b3 = bias[cb + 3];
    } else {
        const u16* bias = (const u16*)biasv;
        b0 = bf2f(bias[cb]); b1 = bf2f(bias[cb + 1]);
        b2 = bf2f(bias[cb + 2]); b3 = bf2f(bias[cb + 3]);
    }
    float vx = ax * inv + b0;
    float vy = ay * inv + b1;
    float vz = az * inv + b2;
    float vw = aw * inv + b3;

    float part;
    if (c4 < 16) {
        part = 0.5f * (vx * vx + vy * vy + vz * vz + vw * vw);
        long long o = (long long)node * 64 + head * 16 + c4;
        stout(outv, o + 0, vx, f32); stout(outv, o + 1, vy, f32);
        stout(outv, o + 2, vz, f32); stout(outv, o + 3, vw, f32);
        long long om = (long long)MEAN_OFF + o;
        stout(outv, om + 0, vx, f32); stout(outv, om + 1, vy, f32);
        stout(outv, om + 2, vz, f32); stout(outv, om + 3, vw, f32);
    } else {
        float s0 = softplusf(vx - 5.f) + 1e-10f;
        float s1 = softplusf(vy - 5.f) + 1e-10f;
        float s2 = softplusf(vz - 5.f) + 1e-10f;
        float s3 = softplusf(vw - 5.f) + 1e-10f;
        part = (-logf(s0) + 0.5f * s0 * s0 - 0.5f)
             + (-logf(s1) + 0.5f * s1 * s1 - 0.5f)
             + (-logf(s2) + 0.5f * s2 * s2 - 0.5f)
             + (-logf(s3) + 0.5f * s3 * s3 - 0.5f);
        long long os = (long long)STD_OFF + (long long)node * 64 + head * 16 + (c4 - 16);
        stout(outv, os + 0, s0, f32); stout(outv, os + 1, s1, f32);
        stout(outv, os + 2, s2, f32); stout(outv, os + 3, s3, f32);
    }
    part = red32(part);
    if (l == 0) stout(outv, (long long)IXZ_OFF + node, part * 0.25f, f32);
    if (t == 0) stout(outv, (long long)SKL_OFF, 0.f, f32);
}

// ---------------------------------------------------------------------------
extern "C" void kernel_launch(void* const* d_in, const int* in_sizes, int n_in,
                              void* d_out, int out_size, void* d_ws, size_t ws_size,
                              hipStream_t stream)
{
    const void* x    = d_in[0];
    const int*  ei   = (const int*)d_in[1];
    const void* w    = d_in[2];
    const void* att  = d_in[3];
    const void* bias = d_in[4];

    const int E = in_sizes[1] / 2;
    const int* src = ei;
    const int* dst = ei + E;

    // workspace layout (~17.9 MB)
    u16*   hb        = (u16*)d_ws;                    // NN*128 bf16
    float* ai        = (float*)(hb + (size_t)NN * 128);
    float* aj        = ai + NN * 4;
    int*   perm_src  = (int*)(aj + NN * 4);           // E
    int*   counts    = perm_src + E;                  // NN
    int*   cursor    = counts + NN;                   // NN
    int*   lexcl     = cursor + NN;                   // NN
    int*   blocksum  = lexcl + NN;                    // NB
    int*   blockoff  = blocksum + NB;                 // NB
    int*   flag      = blockoff + NB;                 // 1
    u16*   wtg       = (u16*)(flag + 1);              // 128*WTS bf16 (padded W^T)

    k_detect<<<1, 64, 0, stream>>>((const u32*)x, flag);
    k_wt<<<8, 256, 0, stream>>>(w, flag, wtg);
    hipMemsetAsync(counts, 0, sizeof(int) * 2 * NN, stream);
    k_gemm<<<(NN + 63) / 64, 256, 0, stream>>>(x, wtg, att, flag, hb, ai, aj);
    k_count<<<(E + 255) / 256, 256, 0, stream>>>(dst, counts, E);
    k_scan1<<<NB, 256, 0, stream>>>(counts, lexcl, blocksum);
    k_scan2<<<1, 256, 0, stream>>>(blocksum, blockoff);
    k_fill<<<(E + 255) / 256, 256, 0, stream>>>(src, dst, lexcl, blockoff,
                                                cursor, perm_src, E);
    k_agg<<<(NN * 32 + 255) / 256, 256, 0, stream>>>(lexcl, blockoff, counts,
                                                     perm_src, ai, aj, hb, bias,
                                                     flag, d_out);
}

// Round 5
// 227.303 us; speedup vs baseline: 1.7326x; 1.0895x over previous
//
#include <hip/hip_runtime.h>
#include <stdint.h>

#define NN 50000
#define NB 196              // ceil(NN/256)
#define NEG_SLOPE 0.2f
#define WTS 136             // padded W^T row stride (u16): 128 + 8 -> conflict-spread b128

// output layout (element offsets)
#define IXZ_OFF    (NN * 64)
#define SKL_OFF    (NN * 64 + NN)
#define MEAN_OFF   (NN * 64 + NN + 1)
#define STD_OFF    (MEAN_OFF + NN * 64)

typedef unsigned int u32;
typedef unsigned short u16;
typedef __attribute__((ext_vector_type(8))) short short8;   // 8 bf16 = 4 VGPRs (MFMA A/B frag)
typedef __attribute__((ext_vector_type(4))) float f32x4;    // MFMA C/D frag

__device__ __forceinline__ float bf2f(u16 s) { return __uint_as_float(((u32)s) << 16); }
__device__ __forceinline__ u16 f2bf(float f) {
    u32 u = __float_as_uint(f);
    u += 0x7FFFu + ((u >> 16) & 1u);   // RNE
    return (u16)(u >> 16);
}
__device__ __forceinline__ float lo16(u32 u) { return __uint_as_float(u << 16); }
__device__ __forceinline__ float hi16(u32 u) { return __uint_as_float(u & 0xFFFF0000u); }
__device__ __forceinline__ float red32(float v) {
    v += __shfl_xor(v, 16); v += __shfl_xor(v, 8); v += __shfl_xor(v, 4);
    v += __shfl_xor(v, 2);  v += __shfl_xor(v, 1);
    return v;
}
__device__ __forceinline__ float softplusf(float x) {
    return fmaxf(x, 0.f) + log1pf(expf(-fabsf(x)));
}
__device__ __forceinline__ void stout(void* o, long long idx, float v, bool f32) {
    if (f32) ((float*)o)[idx] = v;
    else     ((u16*)o)[idx]   = f2bf(v);
}
__device__ __forceinline__ int wscan_incl(int v, int lane) {
#pragma unroll
    for (int off = 1; off < 64; off <<= 1) {
        int u = __shfl_up(v, off);
        if (lane >= off) v += u;
    }
    return v;
}

// ---------------------------------------------------------------------------
// dtype detection: bf16 data -> low u16 of each dword has a sane bf16 exponent
// ---------------------------------------------------------------------------
__global__ void k_detect(const u32* __restrict__ xw, int* __restrict__ flag)
{
    int t = threadIdx.x;            // 64 threads
    u32 wrd = xw[t];
    u32 e = (wrd >> 7) & 0xFF;
    bool plaus = (e >= 0x60 && e <= 0x85);
    unsigned long long b = __ballot(plaus);
    if (t == 0) flag[0] = (__popcll(b) < 32) ? 1 : 0;   // 1 => fp32 storage
}

// ---------------------------------------------------------------------------
// k_wt: W (k,c) -> global padded W^T image (bf16), rows = channel, stride WTS.
// ---------------------------------------------------------------------------
__global__ __launch_bounds__(256) void k_wt(const void* __restrict__ wv_,
                                            const int* __restrict__ flag,
                                            u16* __restrict__ wtg)
{
    const int t = threadIdx.x;
    const int k = blockIdx.x * 16 + (t >> 4);
    const int cq = t & 15;
    const bool f32 = flag[0] != 0;
    u16 v[8];
    if (f32) {
        const float* w = (const float*)wv_;
        float4 a = *(const float4*)(w + k * 128 + cq * 8);
        float4 b = *(const float4*)(w + k * 128 + cq * 8 + 4);
        v[0] = f2bf(a.x); v[1] = f2bf(a.y); v[2] = f2bf(a.z); v[3] = f2bf(a.w);
        v[4] = f2bf(b.x); v[5] = f2bf(b.y); v[6] = f2bf(b.z); v[7] = f2bf(b.w);
    } else {
        const u16* w = (const u16*)wv_;
        uint4 u = *(const uint4*)(w + k * 128 + cq * 8);
        v[0] = (u16)(u.x & 0xFFFF); v[1] = (u16)(u.x >> 16);
        v[2] = (u16)(u.y & 0xFFFF); v[3] = (u16)(u.y >> 16);
        v[4] = (u16)(u.z & 0xFFFF); v[5] = (u16)(u.z >> 16);
        v[6] = (u16)(u.w & 0xFFFF); v[7] = (u16)(u.w >> 16);
    }
#pragma unroll
    for (int j = 0; j < 8; j++)
        wtg[(cq * 8 + j) * WTS + k] = v[j];
}

// ---------------------------------------------------------------------------
// MFMA GEMM: h = x @ W. Wave = 16 nodes x 128 ch, 32x mfma_f32_16x16x32_bf16.
// ---------------------------------------------------------------------------
__global__ __launch_bounds__(256) void k_gemm(
    const void* __restrict__ xv, const u16* __restrict__ wtg,
    const void* __restrict__ attv, const int* __restrict__ flag,
    u16* __restrict__ hb, float* __restrict__ ai, float* __restrict__ aj)
{
    __shared__ __align__(16) u16 ls[128 * WTS];   // 34816 B
    const int tid = threadIdx.x;
    const bool f32 = flag[0] != 0;

    {
        uint4* d = (uint4*)ls;
        const uint4* s = (const uint4*)wtg;
        for (int i = tid; i < 128 * WTS / 8; i += 256) d[i] = s[i];
    }

    const int w = tid >> 6, L = tid & 63;
    const int q = L >> 4, c15 = L & 15;
    const int nb16 = blockIdx.x * 64 + w * 16;

    short8 afr[4];
    {
        int nrow = nb16 + c15; if (nrow > NN - 1) nrow = NN - 1;
        if (f32) {
            const float* xp = (const float*)xv + (size_t)nrow * 128 + q * 8;
#pragma unroll
            for (int ks = 0; ks < 4; ks++) {
                float4 a = *(const float4*)(xp + ks * 32);
                float4 b = *(const float4*)(xp + ks * 32 + 4);
                union { short8 s; u16 e[8]; } u;
                u.e[0] = f2bf(a.x); u.e[1] = f2bf(a.y); u.e[2] = f2bf(a.z); u.e[3] = f2bf(a.w);
                u.e[4] = f2bf(b.x); u.e[5] = f2bf(b.y); u.e[6] = f2bf(b.z); u.e[7] = f2bf(b.w);
                afr[ks] = u.s;
            }
        } else {
            const u16* xp = (const u16*)xv + (size_t)nrow * 128 + q * 8;
#pragma unroll
            for (int ks = 0; ks < 4; ks++)
                afr[ks] = *(const short8*)(xp + ks * 32);
        }
    }
    __syncthreads();

    f32x4 acc[8];
#pragma unroll
    for (int t = 0; t < 8; t++) {
        acc[t] = (f32x4){0.f, 0.f, 0.f, 0.f};
        const u16* bp = ls + (16 * t + c15) * WTS + q * 8;
#pragma unroll
        for (int ks = 0; ks < 4; ks++) {
            short8 bfr = *(const short8*)(bp + ks * 32);
            acc[t] = __builtin_amdgcn_mfma_f32_16x16x32_bf16(afr[ks], bfr, acc[t], 0, 0, 0);
        }
    }

    float ati[8], atj[8];
#pragma unroll
    for (int t = 0; t < 8; t++) {
        int p = (t >> 1) * 64 + (t & 1) * 16 + c15;
        if (f32) {
            ati[t] = ((const float*)attv)[p];
            atj[t] = ((const float*)attv)[p + 32];
        } else {
            ati[t] = bf2f(((const u16*)attv)[p]);
            atj[t] = bf2f(((const u16*)attv)[p + 32]);
        }
    }
#pragma unroll
    for (int r = 0; r < 4; r++) {
        int node = nb16 + q * 4 + r;
#pragma unroll
        for (int h = 0; h < 4; h++) {
            float pi = acc[2 * h][r] * ati[2 * h] + acc[2 * h + 1][r] * ati[2 * h + 1];
            float pj = acc[2 * h][r] * atj[2 * h] + acc[2 * h + 1][r] * atj[2 * h + 1];
            pi += __shfl_xor(pi, 1); pj += __shfl_xor(pj, 1);
            pi += __shfl_xor(pi, 2); pj += __shfl_xor(pj, 2);
            pi += __shfl_xor(pi, 4); pj += __shfl_xor(pj, 4);
            pi += __shfl_xor(pi, 8); pj += __shfl_xor(pj, 8);
            if (c15 == 0 && node < NN) { ai[node * 4 + h] = pi; aj[node * 4 + h] = pj; }
        }
    }

    __syncthreads();
    u16* myls = ls + w * 16 * WTS;
#pragma unroll
    for (int t = 0; t < 8; t++)
#pragma unroll
        for (int r = 0; r < 4; r++)
            myls[(q * 4 + r) * WTS + 16 * t + c15] = f2bf(acc[t][r]);
#pragma unroll
    for (int v = 0; v < 4; v++) {
        int idx = v * 64 + L;
        int nrow = idx >> 4, c8 = idx & 15;
        int node = nb16 + nrow;
        if (node < NN)
            *(uint4*)(hb + (size_t)node * 128 + c8 * 8) =
                *(const uint4*)(myls + nrow * WTS + c8 * 8);
    }
}

// ---------------------------------------------------------------------------
// CSR build: count, hierarchical scan (2 levels), fill
// ---------------------------------------------------------------------------
__global__ __launch_bounds__(256) void k_count(const int* __restrict__ dst,
                                               int* __restrict__ counts, int E)
{
    int e = blockIdx.x * 256 + threadIdx.x;
    if (e < E) atomicAdd(&counts[dst[e]], 1);
}

__global__ __launch_bounds__(256) void k_scan1(const int* __restrict__ counts,
                                               int* __restrict__ lexcl,
                                               int* __restrict__ blocksum)
{
    __shared__ int wsum[4];
    const int t = threadIdx.x, lane = t & 63, wv = t >> 6;
    const int i = blockIdx.x * 256 + t;
    int c = (i < NN) ? counts[i] : 0;
    int inc = wscan_incl(c, lane);
    if (lane == 63) wsum[wv] = inc;
    __syncthreads();
    int add = 0;
#pragma unroll
    for (int k = 0; k < 3; k++) if (k < wv) add += wsum[k];
    inc += add;
    if (i < NN) lexcl[i] = inc - c;
    if (t == 255) blocksum[blockIdx.x] = inc;
}

__global__ __launch_bounds__(256) void k_scan2(const int* __restrict__ blocksum,
                                               int* __restrict__ blockoff)
{
    __shared__ int wsum[4];
    const int t = threadIdx.x, lane = t & 63, wv = t >> 6;
    int c = (t < NB) ? blocksum[t] : 0;
    int inc = wscan_incl(c, lane);
    if (lane == 63) wsum[wv] = inc;
    __syncthreads();
    int add = 0;
#pragma unroll
    for (int k = 0; k < 3; k++) if (k < wv) add += wsum[k];
    inc += add;
    if (t < NB) blockoff[t] = inc - c;
}

__global__ __launch_bounds__(256) void k_fill(
    const int* __restrict__ src, const int* __restrict__ dst,
    const int* __restrict__ lexcl, const int* __restrict__ blockoff,
    int* __restrict__ cursor, int* __restrict__ perm_src, int E)
{
    int e = blockIdx.x * 256 + threadIdx.x;
    if (e >= E) return;
    int d = dst[e];
    int pos = blockoff[d >> 8] + lexcl[d] + atomicAdd(&cursor[d], 1);
    perm_src[pos] = src[e];
}

// ---------------------------------------------------------------------------
// Aggregation + finalize: 32 threads/node, lane l -> channels 4l..4l+3,
// head = l>>3. SINGLE pass: no softmax max-subtraction (|alpha| <= ~8, exp
// safe in fp32; result identical to max-subtracted form up to rounding).
// ---------------------------------------------------------------------------
__global__ __launch_bounds__(256) void k_agg(
    const int* __restrict__ lexcl, const int* __restrict__ blockoff,
    const int* __restrict__ counts, const int* __restrict__ perm_src,
    const float* __restrict__ ai, const float* __restrict__ aj,
    const u16* __restrict__ hb, const void* __restrict__ biasv,
    const int* __restrict__ flag, void* __restrict__ outv)
{
    const int t = blockIdx.x * 256 + threadIdx.x;
    const int node = t >> 5;
    if (node >= NN) return;
    const bool f32 = flag[0] != 0;
    const int l = t & 31;
    const int head = l >> 3;
    const int c4 = (l & 7) << 2;

    const int rs = blockoff[node >> 8] + lexcl[node];
    const int re = rs + counts[node];
    const float ain = ai[node * 4 + head];

    float dsum = 0.f, ax = 0.f, ay = 0.f, az = 0.f, aw = 0.f;
    for (int i = rs; i < re; i++) {
        int s = perm_src[i];
        float a = aj[s * 4 + head] + ain;
        a = a > 0.f ? a : NEG_SLOPE * a;
        float ev = __expf(a);
        dsum += ev;
        uint2 hv = *(const uint2*)(hb + (size_t)s * 128 + l * 4);
        ax += ev * lo16(hv.x); ay += ev * hi16(hv.x);
        az += ev * lo16(hv.y); aw += ev * hi16(hv.y);
    }
    const float inv = 1.f / (dsum + 1e-16f);
    const int cb = head * 32 + c4;
    float b0, b1, b2, b3;
    if (f32) {
        const float* bias = (const float*)biasv;
        b0 = bias[cb]; b1 = bias[cb + 1]; b2 = bias[cb + 2]; b3 = bias[cb + 3];
    } else {
        const u16* bias = (const u16*)biasv;
        b0 = bf2f(bias[cb]); b1 = bf2f(bias[cb + 1]);
        b2 = bf2f(bias[cb + 2]); b3 = bf2f(bias[cb + 3]);
    }
    float vx = ax * inv + b0;
    float vy = ay * inv + b1;
    float vz = az * inv + b2;
    float vw = aw * inv + b3;

    float part;
    if (c4 < 16) {
        part = 0.5f * (vx * vx + vy * vy + vz * vz + vw * vw);
        long long o = (long long)node * 64 + head * 16 + c4;
        stout(outv, o + 0, vx, f32); stout(outv, o + 1, vy, f32);
        stout(outv, o + 2, vz, f32); stout(outv, o + 3, vw, f32);
        long long om = (long long)MEAN_OFF + o;
        stout(outv, om + 0, vx, f32); stout(outv, om + 1, vy, f32);
        stout(outv, om + 2, vz, f32); stout(outv, om + 3, vw, f32);
    } else {
        float s0 = softplusf(vx - 5.f) + 1e-10f;
        float s1 = softplusf(vy - 5.f) + 1e-10f;
        float s2 = softplusf(vz - 5.f) + 1e-10f;
        float s3 = softplusf(vw - 5.f) + 1e-10f;
        part = (-logf(s0) + 0.5f * s0 * s0 - 0.5f)
             + (-logf(s1) + 0.5f * s1 * s1 - 0.5f)
             + (-logf(s2) + 0.5f * s2 * s2 - 0.5f)
             + (-logf(s3) + 0.5f * s3 * s3 - 0.5f);
        long long os = (long long)STD_OFF + (long long)node * 64 + head * 16 + (c4 - 16);
        stout(outv, os + 0, s0, f32); stout(outv, os + 1, s1, f32);
        stout(outv, os + 2, s2, f32); stout(outv, os + 3, s3, f32);
    }
    part = red32(part);
    if (l == 0) stout(outv, (long long)IXZ_OFF + node, part * 0.25f, f32);
    if (t == 0) stout(outv, (long long)SKL_OFF, 0.f, f32);
}

// ---------------------------------------------------------------------------
extern "C" void kernel_launch(void* const* d_in, const int* in_sizes, int n_in,
                              void* d_out, int out_size, void* d_ws, size_t ws_size,
                              hipStream_t stream)
{
    const void* x    = d_in[0];
    const int*  ei   = (const int*)d_in[1];
    const void* w    = d_in[2];
    const void* att  = d_in[3];
    const void* bias = d_in[4];

    const int E = in_sizes[1] / 2;
    const int* src = ei;
    const int* dst = ei + E;

    // workspace layout (~17.9 MB)
    u16*   hb        = (u16*)d_ws;                    // NN*128 bf16
    float* ai        = (float*)(hb + (size_t)NN * 128);
    float* aj        = ai + NN * 4;
    int*   perm_src  = (int*)(aj + NN * 4);           // E
    int*   counts    = perm_src + E;                  // NN
    int*   cursor    = counts + NN;                   // NN
    int*   lexcl     = cursor + NN;                   // NN
    int*   blocksum  = lexcl + NN;                    // NB
    int*   blockoff  = blocksum + NB;                 // NB
    int*   flag      = blockoff + NB;                 // 1
    u16*   wtg       = (u16*)(flag + 1);              // 128*WTS bf16 (padded W^T)

    k_detect<<<1, 64, 0, stream>>>((const u32*)x, flag);
    k_wt<<<8, 256, 0, stream>>>(w, flag, wtg);
    hipMemsetAsync(counts, 0, sizeof(int) * 2 * NN, stream);
    k_gemm<<<(NN + 63) / 64, 256, 0, stream>>>(x, wtg, att, flag, hb, ai, aj);
    k_count<<<(E + 255) / 256, 256, 0, stream>>>(dst, counts, E);
    k_scan1<<<NB, 256, 0, stream>>>(counts, lexcl, blocksum);
    k_scan2<<<1, 256, 0, stream>>>(blocksum, blockoff);
    k_fill<<<(E + 255) / 256, 256, 0, stream>>>(src, dst, lexcl, blockoff,
                                                cursor, perm_src, E);
    k_agg<<<(NN * 32 + 255) / 256, 256, 0, stream>>>(lexcl, blockoff, counts,
                                                     perm_src, ai, aj, hb, bias,
                                                     flag, d_out);
}

// Round 6
// 209.968 us; speedup vs baseline: 1.8757x; 1.0826x over previous
//
#include <hip/hip_runtime.h>
#include <stdint.h>

#define NN 50000
#define NB 196              // ceil(NN/256)
#define NEG_SLOPE 0.2f
#define WTS 136             // padded W^T row stride (u16)

// output layout (element offsets)
#define IXZ_OFF    (NN * 64)
#define SKL_OFF    (NN * 64 + NN)
#define MEAN_OFF   (NN * 64 + NN + 1)
#define STD_OFF    (MEAN_OFF + NN * 64)

typedef unsigned int u32;
typedef unsigned short u16;
typedef __attribute__((ext_vector_type(8))) short short8;
typedef __attribute__((ext_vector_type(4))) float f32x4;

__device__ __forceinline__ float bf2f(u16 s) { return __uint_as_float(((u32)s) << 16); }
__device__ __forceinline__ u16 f2bf(float f) {
    u32 u = __float_as_uint(f);
    u += 0x7FFFu + ((u >> 16) & 1u);   // RNE
    return (u16)(u >> 16);
}
__device__ __forceinline__ float lo16(u32 u) { return __uint_as_float(u << 16); }
__device__ __forceinline__ float hi16(u32 u) { return __uint_as_float(u & 0xFFFF0000u); }
__device__ __forceinline__ float softplusf(float x) {
    return fmaxf(x, 0.f) + log1pf(expf(-fabsf(x)));
}
__device__ __forceinline__ void stout(void* o, long long idx, float v, bool f32) {
    if (f32) ((float*)o)[idx] = v;
    else     ((u16*)o)[idx]   = f2bf(v);
}
__device__ __forceinline__ int wscan_incl(int v, int lane) {
#pragma unroll
    for (int off = 1; off < 64; off <<= 1) {
        int u = __shfl_up(v, off);
        if (lane >= off) v += u;
    }
    return v;
}

// ---------------------------------------------------------------------------
// k_wt: (a) dtype-detect from x -> flag, (b) zero counts+cursor,
//       (c) W (k,c) -> padded global W^T image (bf16).
// 8 blocks x 256 threads.
// ---------------------------------------------------------------------------
__global__ __launch_bounds__(256) void k_wt(const u32* __restrict__ xw,
                                            const void* __restrict__ wv_,
                                            int* __restrict__ flag,
                                            u16* __restrict__ wtg,
                                            int* __restrict__ zbase)
{
    __shared__ int lflag;
    const int t = threadIdx.x;
    // detect (wave 0 of each block, independently)
    if (t < 64) {
        u32 wrd = xw[t];
        u32 e = (wrd >> 7) & 0xFF;
        bool plaus = (e >= 0x60 && e <= 0x85);
        unsigned long long b = __ballot(plaus);
        if (t == 0) {
            int f = (__popcll(b) < 32) ? 1 : 0;
            lflag = f;
            if (blockIdx.x == 0) flag[0] = f;
        }
    }
    __syncthreads();
    const bool f32 = lflag != 0;

    // zero counts + cursor (2*NN ints) across the 2048-thread grid
    const int gid = blockIdx.x * 256 + t;
    for (int i = gid; i < 2 * NN; i += 8 * 256) zbase[i] = 0;

    // transpose W
    const int k = blockIdx.x * 16 + (t >> 4);
    const int cq = t & 15;
    u16 v[8];
    if (f32) {
        const float* w = (const float*)wv_;
        float4 a = *(const float4*)(w + k * 128 + cq * 8);
        float4 b = *(const float4*)(w + k * 128 + cq * 8 + 4);
        v[0] = f2bf(a.x); v[1] = f2bf(a.y); v[2] = f2bf(a.z); v[3] = f2bf(a.w);
        v[4] = f2bf(b.x); v[5] = f2bf(b.y); v[6] = f2bf(b.z); v[7] = f2bf(b.w);
    } else {
        const u16* w = (const u16*)wv_;
        uint4 u = *(const uint4*)(w + k * 128 + cq * 8);
        v[0] = (u16)(u.x & 0xFFFF); v[1] = (u16)(u.x >> 16);
        v[2] = (u16)(u.y & 0xFFFF); v[3] = (u16)(u.y >> 16);
        v[4] = (u16)(u.z & 0xFFFF); v[5] = (u16)(u.z >> 16);
        v[6] = (u16)(u.w & 0xFFFF); v[7] = (u16)(u.w >> 16);
    }
#pragma unroll
    for (int j = 0; j < 8; j++)
        wtg[(cq * 8 + j) * WTS + k] = v[j];
}

// ---------------------------------------------------------------------------
// MFMA GEMM: h = x @ W. Wave = 16 nodes x 128 ch, 32x mfma_f32_16x16x32_bf16.
// Tail: grid-stride edge loop doing the dst-degree count (overlaps MFMA).
// ---------------------------------------------------------------------------
__global__ __launch_bounds__(256) void k_gemm(
    const void* __restrict__ xv, const u16* __restrict__ wtg,
    const void* __restrict__ attv, const int* __restrict__ flag,
    u16* __restrict__ hb, float* __restrict__ ai, float* __restrict__ aj,
    const int* __restrict__ dst, int* __restrict__ counts, int E)
{
    __shared__ __align__(16) u16 ls[128 * WTS];   // 34816 B
    const int tid = threadIdx.x;
    const bool f32 = flag[0] != 0;

    {
        uint4* d = (uint4*)ls;
        const uint4* s = (const uint4*)wtg;
        for (int i = tid; i < 128 * WTS / 8; i += 256) d[i] = s[i];
    }

    const int w = tid >> 6, L = tid & 63;
    const int q = L >> 4, c15 = L & 15;
    const int nb16 = blockIdx.x * 64 + w * 16;

    short8 afr[4];
    {
        int nrow = nb16 + c15; if (nrow > NN - 1) nrow = NN - 1;
        if (f32) {
            const float* xp = (const float*)xv + (size_t)nrow * 128 + q * 8;
#pragma unroll
            for (int ks = 0; ks < 4; ks++) {
                float4 a = *(const float4*)(xp + ks * 32);
                float4 b = *(const float4*)(xp + ks * 32 + 4);
                union { short8 s; u16 e[8]; } u;
                u.e[0] = f2bf(a.x); u.e[1] = f2bf(a.y); u.e[2] = f2bf(a.z); u.e[3] = f2bf(a.w);
                u.e[4] = f2bf(b.x); u.e[5] = f2bf(b.y); u.e[6] = f2bf(b.z); u.e[7] = f2bf(b.w);
                afr[ks] = u.s;
            }
        } else {
            const u16* xp = (const u16*)xv + (size_t)nrow * 128 + q * 8;
#pragma unroll
            for (int ks = 0; ks < 4; ks++)
                afr[ks] = *(const short8*)(xp + ks * 32);
        }
    }
    __syncthreads();

    f32x4 acc[8];
#pragma unroll
    for (int t = 0; t < 8; t++) {
        acc[t] = (f32x4){0.f, 0.f, 0.f, 0.f};
        const u16* bp = ls + (16 * t + c15) * WTS + q * 8;
#pragma unroll
        for (int ks = 0; ks < 4; ks++) {
            short8 bfr = *(const short8*)(bp + ks * 32);
            acc[t] = __builtin_amdgcn_mfma_f32_16x16x32_bf16(afr[ks], bfr, acc[t], 0, 0, 0);
        }
    }

    float ati[8], atj[8];
#pragma unroll
    for (int t = 0; t < 8; t++) {
        int p = (t >> 1) * 64 + (t & 1) * 16 + c15;
        if (f32) {
            ati[t] = ((const float*)attv)[p];
            atj[t] = ((const float*)attv)[p + 32];
        } else {
            ati[t] = bf2f(((const u16*)attv)[p]);
            atj[t] = bf2f(((const u16*)attv)[p + 32]);
        }
    }
#pragma unroll
    for (int r = 0; r < 4; r++) {
        int node = nb16 + q * 4 + r;
#pragma unroll
        for (int h = 0; h < 4; h++) {
            float pi = acc[2 * h][r] * ati[2 * h] + acc[2 * h + 1][r] * ati[2 * h + 1];
            float pj = acc[2 * h][r] * atj[2 * h] + acc[2 * h + 1][r] * atj[2 * h + 1];
            pi += __shfl_xor(pi, 1); pj += __shfl_xor(pj, 1);
            pi += __shfl_xor(pi, 2); pj += __shfl_xor(pj, 2);
            pi += __shfl_xor(pi, 4); pj += __shfl_xor(pj, 4);
            pi += __shfl_xor(pi, 8); pj += __shfl_xor(pj, 8);
            if (c15 == 0 && node < NN) { ai[node * 4 + h] = pi; aj[node * 4 + h] = pj; }
        }
    }

    __syncthreads();
    u16* myls = ls + w * 16 * WTS;
#pragma unroll
    for (int t = 0; t < 8; t++)
#pragma unroll
        for (int r = 0; r < 4; r++)
            myls[(q * 4 + r) * WTS + 16 * t + c15] = f2bf(acc[t][r]);
#pragma unroll
    for (int v = 0; v < 4; v++) {
        int idx = v * 64 + L;
        int nrow = idx >> 4, c8 = idx & 15;
        int node = nb16 + nrow;
        if (node < NN)
            *(uint4*)(hb + (size_t)node * 128 + c8 * 8) =
                *(const uint4*)(myls + nrow * WTS + c8 * 8);
    }

    // fused degree count (independent of GEMM result; overlaps MFMA waves)
    const int gid = blockIdx.x * 256 + tid;
    const int stride = gridDim.x * 256;
    for (int e = gid; e < E; e += stride)
        atomicAdd(&counts[dst[e]], 1);
}

// ---------------------------------------------------------------------------
// hierarchical scan (2 levels)
// ---------------------------------------------------------------------------
__global__ __launch_bounds__(256) void k_scan1(const int* __restrict__ counts,
                                               int* __restrict__ lexcl,
                                               int* __restrict__ blocksum)
{
    __shared__ int wsum[4];
    const int t = threadIdx.x, lane = t & 63, wv = t >> 6;
    const int i = blockIdx.x * 256 + t;
    int c = (i < NN) ? counts[i] : 0;
    int inc = wscan_incl(c, lane);
    if (lane == 63) wsum[wv] = inc;
    __syncthreads();
    int add = 0;
#pragma unroll
    for (int k = 0; k < 3; k++) if (k < wv) add += wsum[k];
    inc += add;
    if (i < NN) lexcl[i] = inc - c;
    if (t == 255) blocksum[blockIdx.x] = inc;
}

__global__ __launch_bounds__(256) void k_scan2(const int* __restrict__ blocksum,
                                               int* __restrict__ blockoff)
{
    __shared__ int wsum[4];
    const int t = threadIdx.x, lane = t & 63, wv = t >> 6;
    int c = (t < NB) ? blocksum[t] : 0;
    int inc = wscan_incl(c, lane);
    if (lane == 63) wsum[wv] = inc;
    __syncthreads();
    int add = 0;
#pragma unroll
    for (int k = 0; k < 3; k++) if (k < wv) add += wsum[k];
    inc += add;
    if (t < NB) blockoff[t] = inc - c;
}

__global__ __launch_bounds__(256) void k_fill(
    const int* __restrict__ src, const int* __restrict__ dst,
    const int* __restrict__ lexcl, const int* __restrict__ blockoff,
    int* __restrict__ cursor, int* __restrict__ perm_src, int E)
{
    int e = blockIdx.x * 256 + threadIdx.x;
    if (e >= E) return;
    int d = dst[e];
    int pos = blockoff[d >> 8] + lexcl[d] + atomicAdd(&cursor[d], 1);
    perm_src[pos] = src[e];
}

// ---------------------------------------------------------------------------
// Aggregation + finalize: 16 threads/node, lane l -> channels 8l..8l+7,
// head = l>>2. Single-pass softmax (no max subtraction; |alpha|<=~8).
// ---------------------------------------------------------------------------
__global__ __launch_bounds__(256) void k_agg(
    const int* __restrict__ lexcl, const int* __restrict__ blockoff,
    const int* __restrict__ counts, const int* __restrict__ perm_src,
    const float* __restrict__ ai, const float* __restrict__ aj,
    const u16* __restrict__ hb, const void* __restrict__ biasv,
    const int* __restrict__ flag, void* __restrict__ outv)
{
    const int t = blockIdx.x * 256 + threadIdx.x;
    const int node = t >> 4;
    if (node >= NN) return;
    const bool f32 = flag[0] != 0;
    const int l = t & 15;
    const int head = l >> 2;
    const int cc0 = (l & 3) << 3;       // within-head channel base: 0,8,16,24

    const int rs = blockoff[node >> 8] + lexcl[node];
    const int re = rs + counts[node];
    const float ain = ai[node * 4 + head];
    const u16* hl8 = hb + l * 8;

    float dsum = 0.f;
    float a0 = 0.f, a1 = 0.f, a2 = 0.f, a3 = 0.f;
    float a4 = 0.f, a5 = 0.f, a6 = 0.f, a7 = 0.f;

    int i = rs;
    for (; i + 1 < re; i += 2) {
        int s0 = perm_src[i], s1 = perm_src[i + 1];
        float x0 = aj[s0 * 4 + head] + ain;
        float x1 = aj[s1 * 4 + head] + ain;
        x0 = x0 > 0.f ? x0 : NEG_SLOPE * x0;
        x1 = x1 > 0.f ? x1 : NEG_SLOPE * x1;
        float e0 = __expf(x0), e1 = __expf(x1);
        uint4 h0 = *(const uint4*)(hl8 + (size_t)s0 * 128);
        uint4 h1 = *(const uint4*)(hl8 + (size_t)s1 * 128);
        dsum += e0 + e1;
        a0 += e0 * lo16(h0.x) + e1 * lo16(h1.x);
        a1 += e0 * hi16(h0.x) + e1 * hi16(h1.x);
        a2 += e0 * lo16(h0.y) + e1 * lo16(h1.y);
        a3 += e0 * hi16(h0.y) + e1 * hi16(h1.y);
        a4 += e0 * lo16(h0.z) + e1 * lo16(h1.z);
        a5 += e0 * hi16(h0.z) + e1 * hi16(h1.z);
        a6 += e0 * lo16(h0.w) + e1 * lo16(h1.w);
        a7 += e0 * hi16(h0.w) + e1 * hi16(h1.w);
    }
    if (i < re) {
        int s0 = perm_src[i];
        float x0 = aj[s0 * 4 + head] + ain;
        x0 = x0 > 0.f ? x0 : NEG_SLOPE * x0;
        float e0 = __expf(x0);
        uint4 h0 = *(const uint4*)(hl8 + (size_t)s0 * 128);
        dsum += e0;
        a0 += e0 * lo16(h0.x); a1 += e0 * hi16(h0.x);
        a2 += e0 * lo16(h0.y); a3 += e0 * hi16(h0.y);
        a4 += e0 * lo16(h0.z); a5 += e0 * hi16(h0.z);
        a6 += e0 * lo16(h0.w); a7 += e0 * hi16(h0.w);
    }

    const float inv = 1.f / (dsum + 1e-16f);
    const int cb = head * 32 + cc0;
    float v[8];
    if (f32) {
        const float* bias = (const float*)biasv;
#pragma unroll
        for (int j = 0; j < 8; j++) v[j] = bias[cb + j];
    } else {
        const u16* bias = (const u16*)biasv;
#pragma unroll
        for (int j = 0; j < 8; j++) v[j] = bf2f(bias[cb + j]);
    }
    v[0] += a0 * inv; v[1] += a1 * inv; v[2] += a2 * inv; v[3] += a3 * inv;
    v[4] += a4 * inv; v[5] += a5 * inv; v[6] += a6 * inv; v[7] += a7 * inv;

    float part = 0.f;
    if (cc0 < 16) {     // mean channels
#pragma unroll
        for (int j = 0; j < 8; j++) part += 0.5f * v[j] * v[j];
        long long o = (long long)node * 64 + head * 16 + cc0;
#pragma unroll
        for (int j = 0; j < 8; j++) stout(outv, o + j, v[j], f32);
        long long om = (long long)MEAN_OFF + o;
#pragma unroll
        for (int j = 0; j < 8; j++) stout(outv, om + j, v[j], f32);
    } else {            // std channels
        long long os = (long long)STD_OFF + (long long)node * 64 + head * 16 + (cc0 - 16);
#pragma unroll
        for (int j = 0; j < 8; j++) {
            float s = softplusf(v[j] - 5.f) + 1e-10f;
            part += -logf(s) + 0.5f * s * s - 0.5f;
            stout(outv, os + j, s, f32);
        }
    }
    part += __shfl_xor(part, 1); part += __shfl_xor(part, 2);
    part += __shfl_xor(part, 4); part += __shfl_xor(part, 8);
    if (l == 0) stout(outv, (long long)IXZ_OFF + node, part * 0.25f, f32);
    if (t == 0) stout(outv, (long long)SKL_OFF, 0.f, f32);
}

// ---------------------------------------------------------------------------
extern "C" void kernel_launch(void* const* d_in, const int* in_sizes, int n_in,
                              void* d_out, int out_size, void* d_ws, size_t ws_size,
                              hipStream_t stream)
{
    const void* x    = d_in[0];
    const int*  ei   = (const int*)d_in[1];
    const void* w    = d_in[2];
    const void* att  = d_in[3];
    const void* bias = d_in[4];

    const int E = in_sizes[1] / 2;
    const int* src = ei;
    const int* dst = ei + E;

    // workspace layout (~17.9 MB)
    u16*   hb        = (u16*)d_ws;                    // NN*128 bf16
    float* ai        = (float*)(hb + (size_t)NN * 128);
    float* aj        = ai + NN * 4;
    int*   perm_src  = (int*)(aj + NN * 4);           // E
    int*   counts    = perm_src + E;                  // NN
    int*   cursor    = counts + NN;                   // NN  (contiguous after counts!)
    int*   lexcl     = cursor + NN;                   // NN
    int*   blocksum  = lexcl + NN;                    // NB
    int*   blockoff  = blocksum + NB;                 // NB
    int*   flag      = blockoff + NB;                 // 1
    u16*   wtg       = (u16*)(flag + 1);              // 128*WTS bf16

    k_wt<<<8, 256, 0, stream>>>((const u32*)x, w, flag, wtg, counts);
    k_gemm<<<(NN + 63) / 64, 256, 0, stream>>>(x, wtg, att, flag, hb, ai, aj,
                                               dst, counts, E);
    k_scan1<<<NB, 256, 0, stream>>>(counts, lexcl, blocksum);
    k_scan2<<<1, 256, 0, stream>>>(blocksum, blockoff);
    k_fill<<<(E + 255) / 256, 256, 0, stream>>>(src, dst, lexcl, blockoff,
                                                cursor, perm_src, E);
    k_agg<<<(NN * 16 + 255) / 256, 256, 0, stream>>>(lexcl, blockoff, counts,
                                                     perm_src, ai, aj, hb, bias,
                                                     flag, d_out);
}